// Round 23
// baseline (110.239 us; speedup 1.0000x reference)
//
#include <hip/hip_runtime.h>
#include <hip/hip_bf16.h>
#include <cstdint>
#include <cstddef>

typedef __bf16 bf16;
typedef __bf16 bf16x2 __attribute__((ext_vector_type(2)));
typedef __bf16 bf16x4 __attribute__((ext_vector_type(4)));
typedef __bf16 bf16x8 __attribute__((ext_vector_type(8)));
typedef float f32x4 __attribute__((ext_vector_type(4)));
typedef float f32x16 __attribute__((ext_vector_type(16)));
typedef unsigned int u32x4 __attribute__((ext_vector_type(4)));

#define S_LEN 2048
#define DM 1024
#define NH 16
#define HD 64
#define NQKV (4096 * 1024)   // tokens * DM
#define NW (1024 * 1024)
// (1/sqrt(64)) * log2(e): fold softmax scale + exp2 conversion into Q
#define QK_SCALE 0.18033688011112042f

__device__ __forceinline__ void gload_lds16(const bf16* g, bf16* l) {
  __builtin_amdgcn_global_load_lds(
      (const __attribute__((address_space(1))) void*)g,
      (__attribute__((address_space(3))) void*)l, 16, 0, 0);
}

__device__ __forceinline__ unsigned packbf(float lo, float hi) {
  bf16x2 t;
  t[0] = (bf16)lo;
  t[1] = (bf16)hi;
  return __builtin_bit_cast(unsigned, t);
}

// v_permlane32_swap_b32: new_a[l>=32] = b_old[l-32]; new_b[l<32] = a_old[l+32]
__device__ __forceinline__ void pl32swap(unsigned& a, unsigned& b) {
#if __has_builtin(__builtin_amdgcn_permlane32_swap)
  auto r = __builtin_amdgcn_permlane32_swap((int)a, (int)b, false, false);
  a = (unsigned)r[0];
  b = (unsigned)r[1];
#else
  asm volatile("v_permlane32_swap_b32 %0, %1" : "+v"(a), "+v"(b));
#endif
}

// ---------------- fused fp32 -> bf16 convert for all 7 tensors ----------------
__global__ __launch_bounds__(256) void cvt_all(
    const float* __restrict__ q, const float* __restrict__ k, const float* __restrict__ v,
    const float* __restrict__ Wq, const float* __restrict__ Wk, const float* __restrict__ Wv,
    const float* __restrict__ Wo, bf16* __restrict__ out) {
  const size_t i = ((size_t)blockIdx.x * 256 + threadIdx.x) * 8;
  const float* src;
  size_t off;
  if (i < (size_t)NQKV) { src = q; off = i; }
  else if (i < 2ull * NQKV) { src = k; off = i - NQKV; }
  else if (i < 3ull * NQKV) { src = v; off = i - 2ull * NQKV; }
  else {
    const size_t j = i - 3ull * NQKV;
    if (j < (size_t)NW) { src = Wq; off = j; }
    else if (j < 2ull * NW) { src = Wk; off = j - NW; }
    else if (j < 3ull * NW) { src = Wv; off = j - 2ull * NW; }
    else { src = Wo; off = j - 3ull * NW; }
  }
  const float4 a = *(const float4*)(src + off);
  const float4 b = *(const float4*)(src + off + 4);
  bf16x8 o;
  o[0] = (bf16)a.x; o[1] = (bf16)a.y; o[2] = (bf16)a.z; o[3] = (bf16)a.w;
  o[4] = (bf16)b.x; o[5] = (bf16)b.y; o[6] = (bf16)b.z; o[7] = (bf16)b.w;
  *(bf16x8*)(out + i) = o;
}

// ------------- output-projection GEMM (r21 proven, 128x128, MODE2 only) --------
__global__ __launch_bounds__(256, 3) void gemm_out(
    const bf16* __restrict__ A, const bf16* __restrict__ W,
    const float* __restrict__ bias0, float* __restrict__ Out,
    int M, int N, int K) {
  __shared__ __align__(16) bf16 sm[3 * 2 * 128 * 32];
  const int tid = threadIdx.x;
  const int lane = tid & 63, w = tid >> 6;
  const int wr = w >> 1, wc = w & 1;
  const int r16 = lane & 15, grp = lane >> 4;

  int flat = blockIdx.y * gridDim.x + blockIdx.x;
  const int cpx = (gridDim.x * gridDim.y) >> 3;
  flat = (flat & 7) * cpx + (flat >> 3);
  const int m0 = (flat / gridDim.x) * 128;
  const int n0 = (flat % gridDim.x) * 128;

  f32x4 acc[4][4] = {};

  int stG[2], stL[2];
#pragma unroll
  for (int j = 0; j < 2; ++j) {
    const int lin = j * 256 + tid;
    const int row = lin >> 2;
    const int ch = (lin & 3) ^ (row & 3);
    stG[j] = row * K + ch * 8;
    stL[j] = lin * 8;
  }

#define GSTAGE(t, s)                                                           \
  {                                                                            \
    const int k0_ = (t) << 5;                                                  \
    bf16* as_ = sm + (s) * 8192;                                               \
    bf16* bs_ = as_ + 4096;                                                    \
    _Pragma("unroll") for (int j = 0; j < 2; ++j) {                            \
      gload_lds16(&A[(size_t)m0 * K + k0_ + stG[j]], &as_[stL[j]]);            \
      gload_lds16(&W[(size_t)n0 * K + k0_ + stG[j]], &bs_[stL[j]]);            \
    }                                                                          \
  }

  const int nk = K >> 5;
  GSTAGE(0, 0)
  GSTAGE(1, 1)

  int cur = 0;
  for (int t = 0; t < nk; ++t) {
    if (t + 1 < nk) asm volatile("s_waitcnt vmcnt(4)" ::: "memory");
    else            asm volatile("s_waitcnt vmcnt(0)" ::: "memory");
    __builtin_amdgcn_s_barrier();

    if (t + 2 < nk) {
      int nxt = cur + 2; if (nxt >= 3) nxt -= 3;
      GSTAGE(t + 2, nxt)
    }

    const char* Asl = (const char*)(sm + cur * 8192);
    const char* Bsl = Asl + 8192;
    {
      bf16x8 af[4], bfr[4];
#pragma unroll
      for (int m = 0; m < 4; ++m) {
        const int row = wr * 64 + m * 16 + r16;
        af[m] = *(const bf16x8*)(Asl + row * 64 + ((grp * 16) ^ ((row & 3) << 4)));
      }
#pragma unroll
      for (int n = 0; n < 4; ++n) {
        const int row = wc * 64 + n * 16 + r16;
        bfr[n] = *(const bf16x8*)(Bsl + row * 64 + ((grp * 16) ^ ((row & 3) << 4)));
      }
#pragma unroll
      for (int m = 0; m < 4; ++m)
#pragma unroll
        for (int n = 0; n < 4; ++n)
          acc[m][n] = __builtin_amdgcn_mfma_f32_16x16x32_bf16(af[m], bfr[n], acc[m][n], 0, 0, 0);
    }
    ++cur; if (cur == 3) cur = 0;
  }
#undef GSTAGE

#pragma unroll
  for (int m = 0; m < 4; ++m)
#pragma unroll
    for (int n = 0; n < 4; ++n)
#pragma unroll
      for (int r = 0; r < 4; ++r) {
        const int row = m0 + wr * 64 + m * 16 + grp * 4 + r;
        const int col = n0 + wc * 64 + n * 16 + r16;
        Out[(size_t)row * N + col] = acc[m][n][r] + bias0[col & 1023];
      }
}

// ------------- fused QKV GEMM: 256x128 tile, 4 waves, BK=32, 3-slot ring -------
// (r22 proven: 32 MFMA/wave/iter amortizes per-iter sync; counted vmcnt(6).)
__global__ __launch_bounds__(256, 2) void gemm_qkv(
    const bf16* __restrict__ A, const bf16* __restrict__ W,
    const float* __restrict__ bias0, const float* __restrict__ bias1,
    const float* __restrict__ bias2, bf16* __restrict__ Out, int K) {
  __shared__ __align__(16) bf16 sm[3 * 12288];  // 3 slots x (A 16KB + B 8KB)
  const int tid = threadIdx.x;
  const int lane = tid & 63, w = tid >> 6;
  const int wr = w >> 1, wc = w & 1;
  const int r16 = lane & 15, grp = lane >> 4;

  int flat = blockIdx.y * gridDim.x + blockIdx.x;
  const int cpx = (gridDim.x * gridDim.y) >> 3;
  flat = (flat & 7) * cpx + (flat >> 3);
  const int m0 = (flat / gridDim.x) * 256;
  const int n0 = (flat % gridDim.x) * 128;

  const int seg = n0 >> 10;
  const bf16* Ab = A + (size_t)seg * NQKV;

  f32x4 acc[8][4] = {};

  int stGA[4], stLA[4], stGB[2], stLB[2];
#pragma unroll
  for (int j = 0; j < 4; ++j) {
    const int lin = j * 256 + tid;
    const int row = lin >> 2;
    const int ch = (lin & 3) ^ (row & 3);
    stGA[j] = row * K + ch * 8;
    stLA[j] = lin * 8;
  }
#pragma unroll
  for (int j = 0; j < 2; ++j) {
    const int lin = j * 256 + tid;
    const int row = lin >> 2;
    const int ch = (lin & 3) ^ (row & 3);
    stGB[j] = row * K + ch * 8;
    stLB[j] = lin * 8;
  }

#define QSTAGE(t, s)                                                           \
  {                                                                            \
    const int k0_ = (t) << 5;                                                  \
    bf16* as_ = sm + (s) * 12288;                                              \
    bf16* bs_ = as_ + 8192;                                                    \
    _Pragma("unroll") for (int j = 0; j < 4; ++j)                              \
      gload_lds16(&Ab[(size_t)m0 * K + k0_ + stGA[j]], &as_[stLA[j]]);         \
    _Pragma("unroll") for (int j = 0; j < 2; ++j)                              \
      gload_lds16(&W[(size_t)n0 * K + k0_ + stGB[j]], &bs_[stLB[j]]);          \
  }

  const int nk = K >> 5;   // 32
  QSTAGE(0, 0)
  QSTAGE(1, 1)

  int cur = 0;
  for (int t = 0; t < nk; ++t) {
    if (t + 1 < nk) asm volatile("s_waitcnt vmcnt(6)" ::: "memory");
    else            asm volatile("s_waitcnt vmcnt(0)" ::: "memory");
    __builtin_amdgcn_s_barrier();

    if (t + 2 < nk) {
      int nxt = cur + 2; if (nxt >= 3) nxt -= 3;
      QSTAGE(t + 2, nxt)
    }

    const char* Asl = (const char*)(sm + cur * 12288);
    const char* Bsl = Asl + 16384;
    {
      bf16x8 af[8], bfr[4];
#pragma unroll
      for (int m = 0; m < 8; ++m) {
        const int row = wr * 128 + m * 16 + r16;
        af[m] = *(const bf16x8*)(Asl + row * 64 + ((grp * 16) ^ ((row & 3) << 4)));
      }
#pragma unroll
      for (int n = 0; n < 4; ++n) {
        const int row = wc * 64 + n * 16 + r16;
        bfr[n] = *(const bf16x8*)(Bsl + row * 64 + ((grp * 16) ^ ((row & 3) << 4)));
      }
      __builtin_amdgcn_s_setprio(1);
#pragma unroll
      for (int m = 0; m < 8; ++m)
#pragma unroll
        for (int n = 0; n < 4; ++n)
          acc[m][n] = __builtin_amdgcn_mfma_f32_16x16x32_bf16(af[m], bfr[n], acc[m][n], 0, 0, 0);
      __builtin_amdgcn_s_setprio(0);
    }
    ++cur; if (cur == 3) cur = 0;
  }
#undef QSTAGE

  const float* bp = (seg == 0 ? bias0 : (seg == 1 ? bias1 : bias2));
  const float sc = (seg == 0 ? QK_SCALE : 1.0f);

  if (seg == 2) {
    // ---- V^T epilogue: wave quadrant = 128 s-rows x 64 d-cols, one head ----
    __syncthreads();
    bf16* T = sm + w * (32 * 132);   // per-wave [32 d][128 s], pitch 132
    const int srow_base = m0 + wr * 128;
    const int b = srow_base >> 11;
    const int srow0 = srow_base & 2047;
    const int hh = ((n0 + wc * 64) & 1023) >> 6;
    bf16* base2 = Out + 2 * (size_t)NQKV;
#pragma unroll
    for (int p = 0; p < 2; ++p) {
#pragma unroll
      for (int nn = 0; nn < 2; ++nn) {
        const int n = 2 * p + nn;
        const int cs = (n0 + wc * 64 + n * 16 + r16) & 1023;
        const float bb = bp[cs];
#pragma unroll
        for (int mq = 0; mq < 8; ++mq)
#pragma unroll
          for (int r = 0; r < 4; ++r) {
            const int d_l = nn * 16 + r16;
            const int s_l = mq * 16 + grp * 4 + r;
            T[d_l * 132 + s_l] = (bf16)(acc[mq][n][r] + bb);
          }
      }
      __syncthreads();
#pragma unroll
      for (int j = 0; j < 8; ++j) {
        const int d_l = j * 4 + (lane >> 4);
        const int scnk = lane & 15;
        const uint2 lo = *(const uint2*)&T[d_l * 132 + scnk * 8];
        const uint2 hi = *(const uint2*)&T[d_l * 132 + scnk * 8 + 4];
        const int dd = p * 32 + d_l;
        bf16* dst = base2 + ((size_t)(b * NH + hh) * HD + dd) * S_LEN + srow0 + scnk * 8;
        uint4 val; val.x = lo.x; val.y = lo.y; val.z = hi.x; val.w = hi.y;
        *(uint4*)dst = val;
      }
      __syncthreads();
    }
    return;
  }

  bf16* base = Out + (size_t)seg * NQKV;
#pragma unroll
  for (int m = 0; m < 8; ++m)
#pragma unroll
    for (int n = 0; n < 4; ++n)
#pragma unroll
      for (int r = 0; r < 4; ++r) {
        const int row = m0 + wr * 128 + m * 16 + grp * 4 + r;
        const int col = n0 + wc * 64 + n * 16 + r16;
        const int cs = col & 1023;
        const float v = (acc[m][n][r] + bp[cs]) * sc;
        const int b = row >> 11, s = row & 2047, h = cs >> 6, d = cs & 63;
        base[((size_t)(b * NH + h) * S_LEN + s) * HD + d] = (bf16)v;
      }
}

// ------ causal flash attention: 2-slot ring, 4 blocks/CU (16 waves/CU) ---------
// r13 compute body verbatim (68 VGPR measured -> fits the 128 cap of
// launch_bounds(256,4), no spill). 2-slot ring (32 KB) with the r11-validated
// drain ledger: iter kt: vmcnt(0) [stage(kt) landed -- issued last iter, had a
// full compute phase to land] ; s_barrier ; stage(kt+1 -> slot (kt+1)&1)
// [slot's readers retired: their ds_reads completed before their MFMAs issued
// (lgkmcnt), hence before this barrier] ; compute(kt from slot kt&1).
// Combine scratch: qh=0 -> Kl region, qh=1 -> Vl region (r14-proven layout).
__global__ __launch_bounds__(256, 4) void attn_fwd23(
    const bf16* __restrict__ Qh, const bf16* __restrict__ Kh,
    const bf16* __restrict__ Vt, bf16* __restrict__ AO) {
  __shared__ __align__(16) bf16 Kl[2][64 * 64];
  __shared__ __align__(16) bf16 Vl[2][64 * 64];

  const int tid = threadIdx.x;
  const int lane = tid & 63, w = tid >> 6;
  const int q31 = lane & 31, h = lane >> 5;
  const int qh = w >> 1, kh = w & 1;
  const int koff = kh << 5;

  const int bid = blockIdx.x;
  const int xcd = bid & 7;
  const int within = bid >> 3;
  const int bh = xcd * 4 + (within & 3);
  const int c = 31 - (within >> 2);

  const bf16* Qb = Qh + (size_t)bh * S_LEN * HD;
  const bf16* Kb = Kh + (size_t)bh * S_LEN * HD;
  const bf16* Vb = Vt + (size_t)bh * HD * S_LEN;

  int stK[2], stV[2], stL[2];
#pragma unroll
  for (int i = 0; i < 2; ++i) {
    const int lin = i * 256 + tid;
    const int row = lin >> 3;
    const int colb = (lin & 7) * 16;
    const int scol = colb ^ ((row & 7) << 4);
    stK[i] = row * HD + (scol >> 1);
    stV[i] = row * S_LEN + (scol >> 1);
    stL[i] = lin * 8;
  }
  const int swz = (q31 & 7) << 4;

#define STAGE(t, buf)                                                          \
  {                                                                            \
    const bf16* kb_ = Kb + (size_t)(t) * 64 * HD;                              \
    const bf16* vb_ = Vb + (t) * 64;                                           \
    _Pragma("unroll") for (int i = 0; i < 2; ++i) {                            \
      gload_lds16(kb_ + stK[i], &Kl[buf][stL[i]]);                             \
      gload_lds16(vb_ + stV[i], &Vl[buf][stL[i]]);                             \
    }                                                                          \
  }

  {
    const int q0 = c << 6;
    const int nt = c + 1;
    const int q0w = q0 + (qh << 5);
    const int qg = q0w + q31;
    const int nt_w = (w == 1) ? nt - 1 : nt;
    const bool maskw = (w == 0) || (w == 3);

    bf16x8 qf[4];
#pragma unroll
    for (int ks = 0; ks < 4; ++ks)
      qf[ks] = *(const bf16x8*)&Qb[(size_t)qg * HD + ks * 16 + 8 * h];

    f32x16 acc0 = {}, acc1 = {};
    float m = -1e30f, l = 0.f;

    STAGE(0, 0)

    for (int kt = 0; kt < nt; ++kt) {
      // stage(kt) landed (issued one iteration ago; full compute phase elapsed)
      asm volatile("s_waitcnt vmcnt(0)" ::: "memory");
      __builtin_amdgcn_s_barrier();
      if (kt + 1 < nt) STAGE(kt + 1, (kt + 1) & 1)

      if (kt < nt_w) {
        const bf16* KlC = &Kl[kt & 1][0];
        const bf16* VlC = &Vl[kt & 1][0];

        bf16x8 kf[4];
#pragma unroll
        for (int ks = 0; ks < 4; ++ks) {
          const int cc = (32 * ks + 16 * h) ^ swz;
          kf[ks] = *(const bf16x8*)((const char*)KlC + (koff + q31) * 128 + cc);
        }

        f32x16 p0 = {};
        __builtin_amdgcn_s_setprio(1);
#pragma unroll
        for (int ks = 0; ks < 4; ++ks)
          p0 = __builtin_amdgcn_mfma_f32_32x32x16_bf16(kf[ks], qf[ks], p0, 0, 0, 0);
        __builtin_amdgcn_s_setprio(0);

        bf16x8 vf[4];
#pragma unroll
        for (int ks = 0; ks < 2; ++ks)
#pragma unroll
          for (int db = 0; db < 2; ++db) {
            const int cc = (64 * kh + 32 * ks + 16 * h) ^ swz;
            vf[ks * 2 + db] =
                *(const bf16x8*)((const char*)VlC + (db * 32 + q31) * 128 + cc);
          }

        if (maskw && kt == nt - 1) {
#pragma unroll
          for (int r = 0; r < 16; ++r) {
            const int key = (kt << 6) + koff + (r & 3) + 8 * (r >> 2) + 4 * h;
            if (key > qg) p0[r] = -1e30f;
          }
        }
        float t_[16];
#pragma unroll
        for (int r = 0; r < 16; ++r) t_[r] = p0[r];
#pragma unroll
        for (int s = 8; s >= 1; s >>= 1)
#pragma unroll
          for (int r = 0; r < s; ++r) t_[r] = fmaxf(t_[r], t_[r + s]);
        const float pmax = fmaxf(t_[0], __shfl_xor(t_[0], 32));
        if (!__all(pmax - m <= 8.0f)) {
          const float mn = fmaxf(m, pmax);
          const float al = exp2f(m - mn);
          m = mn;
          l *= al;
#pragma unroll
          for (int r = 0; r < 16; ++r) { acc0[r] *= al; acc1[r] *= al; }
        }
        float sv[16];
#pragma unroll
        for (int r = 0; r < 16; ++r) {
          p0[r] = exp2f(p0[r] - m);
          sv[r] = p0[r];
        }
#pragma unroll
        for (int s = 8; s >= 1; s >>= 1)
#pragma unroll
          for (int r = 0; r < s; ++r) sv[r] += sv[r + s];
        l += sv[0] + __shfl_xor(sv[0], 32);

        unsigned wv[8];
#pragma unroll
        for (int mm = 0; mm < 8; ++mm)
          wv[mm] = packbf(p0[2 * mm], p0[2 * mm + 1]);
        pl32swap(wv[0], wv[2]);
        pl32swap(wv[1], wv[3]);
        pl32swap(wv[4], wv[6]);
        pl32swap(wv[5], wv[7]);

        __builtin_amdgcn_s_setprio(1);
        {
          u32x4 pu0 = {wv[0], wv[1], wv[2], wv[3]};
          const bf16x8 pf0 = __builtin_bit_cast(bf16x8, pu0);
          acc0 = __builtin_amdgcn_mfma_f32_32x32x16_bf16(vf[0], pf0, acc0, 0, 0, 0);
          acc1 = __builtin_amdgcn_mfma_f32_32x32x16_bf16(vf[1], pf0, acc1, 0, 0, 0);
          u32x4 pu1 = {wv[4], wv[5], wv[6], wv[7]};
          const bf16x8 pf1 = __builtin_bit_cast(bf16x8, pu1);
          acc0 = __builtin_amdgcn_mfma_f32_32x32x16_bf16(vf[2], pf1, acc0, 0, 0, 0);
          acc1 = __builtin_amdgcn_mfma_f32_32x32x16_bf16(vf[3], pf1, acc1, 0, 0, 0);
        }
        __builtin_amdgcn_s_setprio(0);
      }
    }

    // ---- split-K combine: qh=0 -> Kl region, qh=1 -> Vl region (8.7KB each) ----
    float* s = (qh ? (float*)&Vl[0][0] : (float*)&Kl[0][0]) + (size_t)lane * 34;
    __syncthreads();   // drains vm+lgkm; all ring reads retired -> reuse as scratch
    if (kh) {
#pragma unroll
      for (int r = 0; r < 16; ++r) { s[r] = acc0[r]; s[16 + r] = acc1[r]; }
      s[32] = m;
      s[33] = l;
    }
    __syncthreads();
    if (!kh) {
      const float m1 = s[32], l1 = s[33];
      const float mn = fmaxf(m, m1);
      const float a0 = exp2f(m - mn), a1 = exp2f(m1 - mn);
      const float linv = 1.0f / (a0 * l + a1 * l1);
      const int b = bh >> 4, hh = bh & 15;
      bf16* orow = AO + ((size_t)(b * S_LEN + qg)) * DM + hh * HD;
#pragma unroll
      for (int mm = 0; mm < 4; ++mm) {
        bf16x4 ov0, ov1;
#pragma unroll
        for (int t2 = 0; t2 < 4; ++t2) {
          ov0[t2] = (bf16)((a0 * acc0[4 * mm + t2] + a1 * s[4 * mm + t2]) * linv);
          ov1[t2] = (bf16)((a0 * acc1[4 * mm + t2] + a1 * s[16 + 4 * mm + t2]) * linv);
        }
        *(bf16x4*)&orow[8 * mm + 4 * h] = ov0;
        *(bf16x4*)&orow[32 + 8 * mm + 4 * h] = ov1;
      }
    }
  }
#undef STAGE
}

// ---------------- launch ----------------
extern "C" void kernel_launch(void* const* d_in, const int* in_sizes, int n_in,
                              void* d_out, int out_size, void* d_ws, size_t ws_size,
                              hipStream_t stream) {
  const float* q  = (const float*)d_in[0];
  const float* k  = (const float*)d_in[1];
  const float* v  = (const float*)d_in[2];
  const float* Wq = (const float*)d_in[3];
  const float* bq = (const float*)d_in[4];
  const float* Wk = (const float*)d_in[5];
  const float* bk = (const float*)d_in[6];
  const float* Wv = (const float*)d_in[7];
  const float* bv = (const float*)d_in[8];
  const float* Wo = (const float*)d_in[9];
  const float* bo = (const float*)d_in[10];

  const int NTOK = 2 * S_LEN;          // 4096

  bf16* qb  = (bf16*)d_ws;             // q,k,v bf16: 3 * NQKV (consecutive)
  bf16* Wqb = qb + 3 * (size_t)NQKV;   // Wq,Wk,Wv,Wo bf16: 4 * NW (consecutive)
  bf16* Wob = Wqb + 3 * (size_t)NW;
  bf16* Qh  = Wqb + 4 * (size_t)NW;    // Qh,Kh,Vt bf16: 3 * NQKV (consecutive)
  bf16* Kh  = Qh + (size_t)NQKV;
  bf16* Vt  = Kh + (size_t)NQKV;
  bf16* AO  = Vt + (size_t)NQKV;

  const int cvt_blocks = (3 * NQKV + 4 * NW) / 8 / 256;
  cvt_all<<<cvt_blocks, 256, 0, stream>>>(q, k, v, Wq, Wk, Wv, Wo, qb);

  // fused QKV projection: M=4096, N=3072, K=1024; 256x128 tiles -> grid (24,16)
  gemm_qkv<<<dim3(3 * DM / 128, NTOK / 256), 256, 0, stream>>>(
      qb, Wqb, bq, bk, bv, Qh, DM);

  // attention: 1024 single-chunk blocks x 256 threads, 2-slot ring, 4/CU
  attn_fwd23<<<dim3(1024), 256, 0, stream>>>(Qh, Kh, Vt, AO);

  // output projection -> fp32 d_out (128x128 tiles, r21 proven)
  gemm_out<<<dim3(DM / 128, NTOK / 128), 256, 0, stream>>>(
      AO, Wob, bo, (float*)d_out, NTOK, DM, DM);
}